// Round 4
// baseline (728.548 us; speedup 1.0000x reference)
//
#include <hip/hip_runtime.h>
#include <stdint.h>

#define D 64
constexpr float NEG_SLOPE = 0.2f;

// ce[l] = sum_d We_l[d] * ae_l[d]
__global__ void k_ce(const float* __restrict__ We1, const float* __restrict__ ae1,
                     const float* __restrict__ We2, const float* __restrict__ ae2,
                     float* __restrict__ ce){
  int lane = threadIdx.x;
  float p1 = We1[lane] * ae1[lane];
  float p2 = We2[lane] * ae2[lane];
  #pragma unroll
  for (int off = 32; off; off >>= 1){ p1 += __shfl_xor(p1, off); p2 += __shfl_xor(p2, off); }
  if (lane == 0){ ce[0] = p1; ce[1] = p2; }
}

// h = X @ W (wave-per-row, W in LDS), fused asrc[n]=h.as, adst[n]=h.ad
__global__ __launch_bounds__(256) void k_gemm_dots(
    const float* __restrict__ X, const float* __restrict__ W,
    const float* __restrict__ a_s, const float* __restrict__ a_d,
    float* __restrict__ H, float* __restrict__ asrc, float* __restrict__ adst, int n)
{
  __shared__ float sW[D * D];
  {
    const float4* Wv = (const float4*)W;
    float4* sWv = (float4*)sW;
    #pragma unroll
    for (int t = threadIdx.x; t < D * D / 4; t += 256) sWv[t] = Wv[t];
  }
  int lane = threadIdx.x & 63;
  int wid  = threadIdx.x >> 6;
  float asv = a_s[lane], adv = a_d[lane];
  __syncthreads();
  int r = blockIdx.x * 4 + wid;
  if (r >= n) return;
  float xv = X[(size_t)r * D + lane];
  float acc = 0.f;
  #pragma unroll
  for (int k = 0; k < D; ++k){
    float xk = __shfl(xv, k);
    acc = fmaf(xk, sW[k * D + lane], acc);
  }
  H[(size_t)r * D + lane] = acc;
  float ps = acc * asv, pd = acc * adv;
  #pragma unroll
  for (int off = 32; off; off >>= 1){ ps += __shfl_xor(ps, off); pd += __shfl_xor(pd, off); }
  if (lane == 0){ asrc[r] = ps; adst[r] = pd; }
}

// ---------------- CSR build (once per call) ----------------

__global__ void k_zero(int* __restrict__ deg, int n){
  int i = blockIdx.x * blockDim.x + threadIdx.x;
  if (i < n) deg[i] = 0;
}

__global__ void k_hist(const int* __restrict__ dst, int* __restrict__ deg, int e){
  int i = blockIdx.x * blockDim.x + threadIdx.x;
  if (i < e) atomicAdd(&deg[dst[i]], 1);
}

// block-level inclusive scan (256/block) + block sums
__global__ __launch_bounds__(256) void k_scan1(const int* __restrict__ deg,
    int* __restrict__ incl, int* __restrict__ bsum, int n){
  __shared__ int s[256];
  int tid = threadIdx.x;
  int idx = blockIdx.x * 256 + tid;
  int v = (idx < n) ? deg[idx] : 0;
  s[tid] = v; __syncthreads();
  #pragma unroll
  for (int off = 1; off < 256; off <<= 1){
    int t = (tid >= off) ? s[tid - off] : 0;
    __syncthreads();
    s[tid] += t;
    __syncthreads();
  }
  if (idx < n) incl[idx] = s[tid];
  if (tid == 255) bsum[blockIdx.x] = s[255];
}

// single-wave exclusive scan of block sums (nb <= 512)
__global__ void k_scan2(int* __restrict__ bsum, int nb){
  int lane = threadIdx.x;                // 64 threads
  int per = (nb + 63) / 64;              // <= 8
  int base = lane * per;
  int local[8];
  int s = 0;
  #pragma unroll
  for (int k = 0; k < 8; ++k){
    int idx = base + k;
    int v = (k < per && idx < nb) ? bsum[idx] : 0;
    local[k] = v; s += v;
  }
  int inc = s;
  #pragma unroll
  for (int off = 1; off < 64; off <<= 1){
    int t = __shfl_up(inc, off);
    if (lane >= off) inc += t;
  }
  int run = inc - s;                     // exclusive prefix for this lane
  #pragma unroll
  for (int k = 0; k < 8; ++k){
    int idx = base + k;
    if (k < per && idx < nb){ int v = local[k]; bsum[idx] = run; run += v; }
  }
}

// rowptr[i+1] = incl[i]+bsum_excl[blk]; cursor[i] = start offset; rowptr[0]=0
__global__ void k_scan3(const int* __restrict__ deg, const int* __restrict__ incl,
    const int* __restrict__ bsum, int* __restrict__ rowptr, int* __restrict__ cursor, int n){
  int idx = blockIdx.x * 256 + threadIdx.x;
  if (idx >= n) return;
  int inc = incl[idx] + bsum[blockIdx.x];
  rowptr[idx + 1] = inc;
  cursor[idx] = inc - deg[idx];
  if (idx == 0) rowptr[0] = 0;
}

// one 8B random store per edge (src, ea-bits packed)
__global__ void k_scatter(const int* __restrict__ src, const int* __restrict__ dst,
    const float* __restrict__ ea, int* __restrict__ cursor,
    int2* __restrict__ edges, int e){
  int i = blockIdx.x * blockDim.x + threadIdx.x;
  if (i >= e) return;
  int d = dst[i];
  int pos = atomicAdd(&cursor[d], 1);
  edges[pos] = make_int2(src[i], __float_as_int(ea[i]));
}

// ---------------- fused per-node softmax + aggregation ----------------
// wave per node, lane=feature. Phase A: lane l holds edge l's (src, alpha) in
// registers (deg<=64 fast path); shfl-reduce max & denom. Phase B: broadcast
// (src_k, e_k) via shfl, accumulate coalesced H rows. No esort buffer.
__global__ __launch_bounds__(256) void k_node_fused(
    const int* __restrict__ rowptr, const int2* __restrict__ edges,
    const float* __restrict__ asrc, const float* __restrict__ adst,
    const float* __restrict__ ce, int ce_idx,
    const float* __restrict__ H, const float* __restrict__ bias,
    float* __restrict__ out, int n, int relu)
{
  int v = blockIdx.x * 4 + (threadIdx.x >> 6);
  int lane = threadIdx.x & 63;
  if (v >= n) return;
  int start = rowptr[v], end = rowptr[v + 1];
  int deg = end - start;
  float bv = bias[lane];
  if (deg == 0){
    float r = relu ? fmaxf(bv, 0.f) : bv;
    out[(size_t)v * D + lane] = r;
    return;
  }
  float adv = adst[v];
  float cev = ce[ce_idx];
  float acc = 0.f;
  float inv;
  if (deg <= 64){
    int my_s = 0; float my_a = -1e30f;
    if (lane < deg){
      int2 pr = edges[start + lane];
      my_s = pr.x;
      float a = asrc[pr.x] + adv + __int_as_float(pr.y) * cev;
      my_a = a > 0.f ? a : NEG_SLOPE * a;
    }
    float m = my_a;
    #pragma unroll
    for (int off = 32; off; off >>= 1) m = fmaxf(m, __shfl_xor(m, off));
    float my_e = (lane < deg) ? __expf(my_a - m) : 0.f;
    float ss = my_e;
    #pragma unroll
    for (int off = 32; off; off >>= 1) ss += __shfl_xor(ss, off);
    inv = 1.f / (ss + 1e-16f);
    for (int k = 0; k < deg; ++k){
      int s   = __shfl(my_s, k);
      float w = __shfl(my_e, k);
      acc = fmaf(H[(size_t)s * D + lane], w, acc);
    }
  } else {
    // generic chunked path (deg > 64) — rare with random edges
    float m = -1e30f;
    for (int j = start + lane; j < end; j += 64){
      int2 pr = edges[j];
      float a = asrc[pr.x] + adv + __int_as_float(pr.y) * cev;
      a = a > 0.f ? a : NEG_SLOPE * a;
      m = fmaxf(m, a);
    }
    #pragma unroll
    for (int off = 32; off; off >>= 1) m = fmaxf(m, __shfl_xor(m, off));
    float ss = 0.f;
    for (int j0 = start; j0 < end; j0 += 64){
      int j = j0 + lane;
      int my_s = 0; float my_e = 0.f;
      if (j < end){
        int2 pr = edges[j];
        float a = asrc[pr.x] + adv + __int_as_float(pr.y) * cev;
        a = a > 0.f ? a : NEG_SLOPE * a;
        my_e = __expf(a - m);
        my_s = pr.x;
      }
      ss += my_e;
      int cnt = min(64, end - j0);
      for (int k = 0; k < cnt; ++k){
        int s   = __shfl(my_s, k);
        float w = __shfl(my_e, k);
        acc = fmaf(H[(size_t)s * D + lane], w, acc);
      }
    }
    #pragma unroll
    for (int off = 32; off; off >>= 1) ss += __shfl_xor(ss, off);
    inv = 1.f / (ss + 1e-16f);
  }
  float r = acc * inv + bv;
  if (relu) r = fmaxf(r, 0.f);
  out[(size_t)v * D + lane] = r;
}

extern "C" void kernel_launch(void* const* d_in, const int* in_sizes, int n_in,
                              void* d_out, int out_size, void* d_ws, size_t ws_size,
                              hipStream_t stream)
{
  const float* x    = (const float*)d_in[0];
  const int*   ei   = (const int*)d_in[1];    // integer inputs arrive as int32
  const float* ea   = (const float*)d_in[2];
  const float* W1   = (const float*)d_in[3];
  const float* We1  = (const float*)d_in[4];
  const float* as1  = (const float*)d_in[5];
  const float* ad1  = (const float*)d_in[6];
  const float* ae1  = (const float*)d_in[7];
  const float* b1   = (const float*)d_in[8];
  const float* W2   = (const float*)d_in[9];
  const float* We2  = (const float*)d_in[10];
  const float* as2  = (const float*)d_in[11];
  const float* ad2  = (const float*)d_in[12];
  const float* ae2  = (const float*)d_in[13];
  const float* b2   = (const float*)d_in[14];
  float* out = (float*)d_out;

  int n = in_sizes[0] / D;     // 100000
  int e = in_sizes[1] / 2;     // 1600000
  const int* srcp = ei;
  const int* dstp = ei + e;

  int nb = (n + 255) / 256;    // scan blocks (391)

  char* p = (char*)d_ws;
  float* buf_h   = (float*)p;  p += (size_t)n * D * 4;
  float* buf_x2  = (float*)p;  p += (size_t)n * D * 4;
  float* asrc    = (float*)p;  p += (size_t)n * 4;
  float* adst    = (float*)p;  p += (size_t)n * 4;
  int*   deg     = (int*)p;    p += (size_t)n * 4;
  int*   incl    = (int*)p;    p += (size_t)n * 4;
  int*   rowptr  = (int*)p;    p += (size_t)(n + 1) * 4;
  int*   cursor  = (int*)p;    p += (size_t)n * 4;
  int*   bsum    = (int*)p;    p += (size_t)(nb + 1) * 4;
  float* ce      = (float*)p;  p += 64;               // keep 8B alignment after
  int2*  edges   = (int2*)p;   p += (size_t)e * 8;

  int gE  = (e + 255) / 256;
  int gR  = (n + 3) / 4;      // wave per node/row, 4 per block

  // ---- CSR build ----
  k_ce<<<1, 64, 0, stream>>>(We1, ae1, We2, ae2, ce);
  k_zero<<<nb, 256, 0, stream>>>(deg, n);
  k_hist<<<gE, 256, 0, stream>>>(dstp, deg, e);
  k_scan1<<<nb, 256, 0, stream>>>(deg, incl, bsum, n);
  k_scan2<<<1, 64, 0, stream>>>(bsum, nb);
  k_scan3<<<nb, 256, 0, stream>>>(deg, incl, bsum, rowptr, cursor, n);
  k_scatter<<<gE, 256, 0, stream>>>(srcp, dstp, ea, cursor, edges, e);

  // ---- layer 1 ----
  k_gemm_dots<<<gR, 256, 0, stream>>>(x, W1, as1, ad1, buf_h, asrc, adst, n);
  k_node_fused<<<gR, 256, 0, stream>>>(rowptr, edges, asrc, adst, ce, 0, buf_h, b1, buf_x2, n, 1);

  // ---- layer 2 ----
  k_gemm_dots<<<gR, 256, 0, stream>>>(buf_x2, W2, as2, ad2, buf_h, asrc, adst, n);
  k_node_fused<<<gR, 256, 0, stream>>>(rowptr, edges, asrc, adst, ce, 1, buf_h, b2, out, n, 0);
}